// Round 3
// baseline (638.223 us; speedup 1.0000x reference)
//
#include <hip/hip_runtime.h>
#include <hip/hip_bf16.h>

// Problem constants
#define NN   2048
#define DD   64
#define HH1  512
#define HH2  512
#define PP   2048
#define EE   16

typedef unsigned short ushort_t;
typedef __attribute__((ext_vector_type(8))) short bf16x8;
typedef __attribute__((ext_vector_type(4))) float f32x4;

__device__ __forceinline__ float b2f(ushort_t u) {
  union { unsigned int i; float f; } v; v.i = ((unsigned int)u) << 16; return v.f;
}
__device__ __forceinline__ ushort_t f2b(float f) {
  union { float f; unsigned int i; } v; v.f = f;
  unsigned int x = v.i;
  unsigned int r = (x + 0x7fffu + ((x >> 16) & 1u)) >> 16;
  return (ushort_t)r;
}
// dtype-aware scalar load: isb ? bf16[i] : fp32[i]
__device__ __forceinline__ float ldf(const void* p, size_t i, int isb) {
  return isb ? b2f(((const ushort_t*)p)[i]) : ((const float*)p)[i];
}

__device__ __forceinline__ void async16(ushort_t* lds, const ushort_t* g) {
  __builtin_amdgcn_global_load_lds(
      (const __attribute__((address_space(1))) void*)g,
      (__attribute__((address_space(3))) void*)lds, 16, 0, 0);
}

// ---------------------------------------------------------------------------
// Dtype sniffer: bf16 buffer -> low 16 bits of each u32 are a valid N(0,1)
// bf16 (exp in [110,135] ~99.9%); fp32 -> those bits are mantissa noise (~10%).
// ---------------------------------------------------------------------------
__global__ void k_sniff(const unsigned int* __restrict__ zraw,
                        int* __restrict__ flag) {
  __shared__ int cnt[256];
  int t = threadIdx.x;
  int c = 0;
  for (int i = t; i < 1024; i += 256) {
    unsigned int u = zraw[i];
    unsigned int e = (u >> 7) & 0xFFu;
    c += (e >= 110u && e <= 135u) ? 1 : 0;
  }
  cnt[t] = c;
  __syncthreads();
  for (int s = 128; s > 0; s >>= 1) {
    if (t < s) cnt[t] += cnt[t + s];
    __syncthreads();
  }
  if (t == 0) *flag = (cnt[0] >= 512) ? 1 : 0;
}

// ---------------------------------------------------------------------------
// MFMA C/D-layout probe: one wave, asymmetric integer A,B (exact in bf16).
// Checks interp0 (m=quad*4+r, n=lane&15) vs interp1 (swapped). mapflag=0/1.
// ---------------------------------------------------------------------------
__global__ void k_probe(int* __restrict__ mapflag) {
  __shared__ ushort_t Ap[16 * 32];
  __shared__ ushort_t Bp[16 * 32];
  int t = threadIdx.x;  // 64 threads
  for (int i = t; i < 512; i += 64) {
    int r = i >> 5, k = i & 31;
    Ap[i] = f2b((float)((r + k) % 7));
    Bp[i] = f2b((float)((2 * r + k) % 5));
  }
  __syncthreads();
  int lr = t & 15, quad = t >> 4;
  bf16x8 a = *(const bf16x8*)&Ap[lr * 32 + quad * 8];
  bf16x8 b = *(const bf16x8*)&Bp[lr * 32 + quad * 8];
  f32x4 acc = {};
  acc = __builtin_amdgcn_mfma_f32_16x16x32_bf16(a, b, acc, 0, 0, 0);
  bool m0 = true, m1 = true;
  for (int r = 0; r < 4; ++r) {
    float r0 = 0.f, r1 = 0.f;
    for (int k = 0; k < 32; ++k) {
      r0 += (float)(((quad * 4 + r) + k) % 7) * (float)((2 * lr + k) % 5);
      r1 += (float)((lr + k) % 7) * (float)((2 * (quad * 4 + r) + k) % 5);
    }
    m0 &= fabsf(acc[r] - r0) < 0.5f;
    m1 &= fabsf(acc[r] - r1) < 0.5f;
  }
  unsigned long long b0 = __ballot(m0);
  unsigned long long b1 = __ballot(m1);
  if (t == 0) *mapflag = (b0 == ~0ULL) ? 0 : ((b1 == ~0ULL) ? 1 : 0);
}

// ---------------------------------------------------------------------------
// Convert input buffer (bf16 or fp32 per flag) to canonical bf16.
// ---------------------------------------------------------------------------
__global__ void k_convert(const void* __restrict__ src,
                          ushort_t* __restrict__ dst, int n,
                          const int* __restrict__ flag) {
  int isb = *flag;
  int stride = gridDim.x * blockDim.x;
  for (int g = blockIdx.x * blockDim.x + threadIdx.x; g * 8 < n; g += stride) {
    int base = g * 8;
    ushort_t ov[8];
    if (isb) {
      *(uint4*)ov = *(const uint4*)((const ushort_t*)src + base);
    } else {
      const float* s = (const float*)src + base;
      float4 f0 = *(const float4*)s;
      float4 f1 = *(const float4*)(s + 4);
      ov[0] = f2b(f0.x); ov[1] = f2b(f0.y); ov[2] = f2b(f0.z); ov[3] = f2b(f0.w);
      ov[4] = f2b(f1.x); ov[5] = f2b(f1.y); ov[6] = f2b(f1.z); ov[7] = f2b(f1.w);
    }
    *(uint4*)(dst + base) = *(uint4*)ov;
  }
}

// ---------------------------------------------------------------------------
// Transpose + convert per-expert weight [K][H] -> [H][K] bf16, 64x64 tiles.
// ---------------------------------------------------------------------------
__global__ void k_transpose_cvt(const void* __restrict__ src_,
                                ushort_t* __restrict__ dst, int K, int H,
                                const int* __restrict__ flag) {
  __shared__ ushort_t tile[64][68];
  int isb = *flag;
  int e = blockIdx.z;
  size_t ebase = (size_t)e * K * H;
  dst += ebase;
  int h0 = blockIdx.x * 64, k0 = blockIdx.y * 64;
  int t = threadIdx.x;
#pragma unroll
  for (int it = 0; it < 2; ++it) {
    int c = it * 256 + t;
    int row = c >> 3, col = (c & 7) * 8;
    size_t idx = ebase + (size_t)(k0 + row) * H + h0 + col;
    ushort_t tmp[8];
    if (isb) {
      *(uint4*)tmp = *(const uint4*)((const ushort_t*)src_ + idx);
    } else {
      const float* s = (const float*)src_ + idx;
      float4 f0 = *(const float4*)s;
      float4 f1 = *(const float4*)(s + 4);
      tmp[0] = f2b(f0.x); tmp[1] = f2b(f0.y); tmp[2] = f2b(f0.z); tmp[3] = f2b(f0.w);
      tmp[4] = f2b(f1.x); tmp[5] = f2b(f1.y); tmp[6] = f2b(f1.z); tmp[7] = f2b(f1.w);
    }
#pragma unroll
    for (int j = 0; j < 8; ++j) tile[row][col + j] = tmp[j];
  }
  __syncthreads();
#pragma unroll
  for (int it = 0; it < 2; ++it) {
    int c = it * 256 + t;
    int row = c >> 3, col = (c & 7) * 8;
    ushort_t tmp[8];
#pragma unroll
    for (int j = 0; j < 8; ++j) tmp[j] = tile[col + j][row];
    *(uint4*)(dst + (size_t)(h0 + row) * K + k0 + col) = *(uint4*)tmp;
  }
}

// ---------------------------------------------------------------------------
// Gate: reads RAW inputs (dtype per flag) in fp32 — exact gate path.
// ---------------------------------------------------------------------------
__global__ void k_gate(const void* __restrict__ z,
                       const void* __restrict__ Wg1,
                       const void* __restrict__ bg1,
                       const void* __restrict__ Wg2,
                       const void* __restrict__ bg2,
                       const int* __restrict__ flag,
                       float* __restrict__ gate) {
  __shared__ float sW1[64][65];
  __shared__ float sW2[64][16];
  __shared__ float sb1[64];
  __shared__ float sb2[16];
  __shared__ float sz[4][64];
  __shared__ float shid[4][64];
  __shared__ float sg[4][16];
  int isb = *flag;
  int t = threadIdx.x;
  for (int i = t; i < 64 * 64; i += 256) sW1[i >> 6][i & 63] = ldf(Wg1, i, isb);
  for (int i = t; i < 64 * 16; i += 256) sW2[i >> 4][i & 15] = ldf(Wg2, i, isb);
  if (t < 64) sb1[t] = ldf(bg1, t, isb);
  if (t < 16) sb2[t] = ldf(bg2, t, isb);
  int w = t >> 6, l = t & 63;
  int n = blockIdx.x * 4 + w;
  sz[w][l] = ldf(z, (size_t)n * DD + l, isb);
  __syncthreads();
  float acc = sb1[l];
#pragma unroll
  for (int d = 0; d < 64; ++d) acc += sz[w][d] * sW1[d][l];
  shid[w][l] = fmaxf(acc, 0.f);
  __syncthreads();
  if (l < 16) {
    float g = sb2[l];
#pragma unroll
    for (int j = 0; j < 64; ++j) g += shid[w][j] * sW2[j][l];
    sg[w][l] = g;
  }
  __syncthreads();
  if (l < 16) {
    float m = -1e30f;
    for (int e2 = 0; e2 < 16; ++e2) m = fmaxf(m, sg[w][e2]);
    float s = 0.f;
    for (int e2 = 0; e2 < 16; ++e2) s += __expf(sg[w][e2] - m);
    gate[(size_t)n * EE + l] = __expf(sg[w][l] - m) / s;
  }
}

// ---------------------------------------------------------------------------
// Batched GEMM: C[e][m][n] = relu( sum_k A[e][m][k]*BT[e][n][k] + bias[e][n] )
// 128x128 tile, BK=32, block 256 (4 waves), mfma 16x16x32 bf16. bf16 out.
// ---------------------------------------------------------------------------
__global__ __launch_bounds__(256) void k_gemm_bt_relu(
    const ushort_t* __restrict__ Aact, const ushort_t* __restrict__ Bt,
    const ushort_t* __restrict__ bias, ushort_t* __restrict__ Cout,
    int M, int Nout, int K,
    long a_stride_e, long b_stride_e, long bias_stride_e, long c_stride_e,
    const int* __restrict__ mapflag) {
  __shared__ ushort_t As[128 * 32];
  __shared__ ushort_t Bs[128 * 32];
  int e = blockIdx.z;
  Aact += (size_t)e * a_stride_e;
  Bt   += (size_t)e * b_stride_e;
  bias += (size_t)e * bias_stride_e;
  Cout += (size_t)e * c_stride_e;
  int m0 = blockIdx.y * 128, n0 = blockIdx.x * 128;
  int t = threadIdx.x;
  int w = t >> 6, l = t & 63;
  int wm = (w >> 1) * 64, wn = (w & 1) * 64;
  int lr = l & 15, quad = l >> 4;
  int mf = *mapflag;

  f32x4 acc[4][4] = {};
  for (int k0 = 0; k0 < K; k0 += 32) {
#pragma unroll
    for (int it = 0; it < 2; ++it) {
      int c = it * 256 + t;
      int row = c >> 2, kk = (c & 3) * 8;
      async16(&As[row * 32 + kk], Aact + (size_t)(m0 + row) * K + k0 + kk);
    }
#pragma unroll
    for (int it = 0; it < 2; ++it) {
      int c = it * 256 + t;
      int row = c >> 2, kk = (c & 3) * 8;
      async16(&Bs[row * 32 + kk], Bt + (size_t)(n0 + row) * K + k0 + kk);
    }
    __syncthreads();
    bf16x8 af[4], bfr[4];
#pragma unroll
    for (int i = 0; i < 4; ++i)
      af[i] = *(const bf16x8*)&As[(wm + i * 16 + lr) * 32 + quad * 8];
#pragma unroll
    for (int j = 0; j < 4; ++j)
      bfr[j] = *(const bf16x8*)&Bs[(wn + j * 16 + lr) * 32 + quad * 8];
#pragma unroll
    for (int i = 0; i < 4; ++i)
#pragma unroll
      for (int j = 0; j < 4; ++j)
        acc[i][j] = __builtin_amdgcn_mfma_f32_16x16x32_bf16(af[i], bfr[j],
                                                            acc[i][j], 0, 0, 0);
    __syncthreads();
  }
  if (mf == 0) {
#pragma unroll
    for (int j = 0; j < 4; ++j) {
      int n = n0 + wn + j * 16 + lr;
      float bv = b2f(bias[n]);
#pragma unroll
      for (int i = 0; i < 4; ++i)
#pragma unroll
        for (int r = 0; r < 4; ++r) {
          int m = m0 + wm + i * 16 + quad * 4 + r;
          Cout[(size_t)m * Nout + n] = f2b(fmaxf(acc[i][j][r] + bv, 0.f));
        }
    }
  } else {
#pragma unroll
    for (int i = 0; i < 4; ++i) {
      int m = m0 + wm + i * 16 + lr;
#pragma unroll
      for (int j = 0; j < 4; ++j)
#pragma unroll
        for (int r = 0; r < 4; ++r) {
          int n = n0 + wn + j * 16 + quad * 4 + r;
          Cout[(size_t)m * Nout + n] = f2b(fmaxf(acc[i][j][r] + b2f(bias[n]), 0.f));
        }
    }
  }
}

// ---------------------------------------------------------------------------
// L3 + gated combine -> fp32 x_rec.
// ---------------------------------------------------------------------------
__global__ __launch_bounds__(512) void k_l3_combine(
    const ushort_t* __restrict__ h2,    // [E][N][512]
    const ushort_t* __restrict__ W3t,   // [E][P][512]
    const ushort_t* __restrict__ b3,    // [E][P] bf16
    const ushort_t* __restrict__ Amat,  // [P][E] bf16
    const float* __restrict__ gate,     // [N][E]
    float* __restrict__ xrec,           // [N][P] fp32
    const int* __restrict__ mapflag) {
  __shared__ ushort_t As[128 * 32];
  __shared__ ushort_t Bs[128 * 32];
  __shared__ float sGate[128][17];
  __shared__ float sA[128][17];
  __shared__ float sB3[16][132];
  int t = threadIdx.x;
  int n0 = blockIdx.y * 128, p0 = blockIdx.x * 128;
  for (int i = t; i < 128 * 16; i += 512) {
    int r = i >> 4, e2 = i & 15;
    sGate[r][e2] = gate[(size_t)(n0 + r) * EE + e2];
    sA[r][e2] = b2f(Amat[(size_t)(p0 + r) * EE + e2]);
  }
  for (int i = t; i < 16 * 128; i += 512) {
    int e2 = i >> 7, c = i & 127;
    sB3[e2][c] = b2f(b3[(size_t)e2 * PP + p0 + c]);
  }
  __syncthreads();
  int w = t >> 6, l = t & 63;
  int wm = (w >> 2) * 64, wn = (w & 3) * 32;
  int lr = l & 15, quad = l >> 4;
  int srow = t >> 2, skk = (t & 3) * 8;
  int mf = *mapflag;

  float weighted[4][2][4] = {};
  float denom[4][2][4] = {};
  for (int e = 0; e < EE; ++e) {
    f32x4 acc[4][2] = {};
    const ushort_t* h2e = h2 + (size_t)e * NN * HH2;
    const ushort_t* w3e = W3t + (size_t)e * PP * HH2;
    for (int k0 = 0; k0 < HH2; k0 += 32) {
      async16(&As[srow * 32 + skk], h2e + (size_t)(n0 + srow) * HH2 + k0 + skk);
      async16(&Bs[srow * 32 + skk], w3e + (size_t)(p0 + srow) * HH2 + k0 + skk);
      __syncthreads();
      bf16x8 af[4], bfr[2];
#pragma unroll
      for (int i = 0; i < 4; ++i)
        af[i] = *(const bf16x8*)&As[(wm + i * 16 + lr) * 32 + quad * 8];
#pragma unroll
      for (int j = 0; j < 2; ++j)
        bfr[j] = *(const bf16x8*)&Bs[(wn + j * 16 + lr) * 32 + quad * 8];
#pragma unroll
      for (int i = 0; i < 4; ++i)
#pragma unroll
        for (int j = 0; j < 2; ++j)
          acc[i][j] = __builtin_amdgcn_mfma_f32_16x16x32_bf16(
              af[i], bfr[j], acc[i][j], 0, 0, 0);
      __syncthreads();
    }
    if (mf == 0) {
#pragma unroll
      for (int i = 0; i < 4; ++i) {
        float g[4];
#pragma unroll
        for (int r = 0; r < 4; ++r) g[r] = sGate[wm + i * 16 + quad * 4 + r][e];
#pragma unroll
        for (int j = 0; j < 2; ++j) {
          int pl = wn + j * 16 + lr;
          float a = sA[pl][e];
          float bb = sB3[e][pl];
#pragma unroll
          for (int r = 0; r < 4; ++r) {
            float wgt = g[r] * a;
            weighted[i][j][r] += wgt * (acc[i][j][r] + bb);
            denom[i][j][r] += wgt;
          }
        }
      }
    } else {
#pragma unroll
      for (int i = 0; i < 4; ++i) {
        float gsc = sGate[wm + i * 16 + lr][e];
#pragma unroll
        for (int j = 0; j < 2; ++j)
#pragma unroll
          for (int r = 0; r < 4; ++r) {
            int pl = wn + j * 16 + quad * 4 + r;
            float wgt = gsc * sA[pl][e];
            weighted[i][j][r] += wgt * (acc[i][j][r] + sB3[e][pl]);
            denom[i][j][r] += wgt;
          }
      }
    }
  }
  if (mf == 0) {
#pragma unroll
    for (int j = 0; j < 2; ++j) {
      int p = p0 + wn + j * 16 + lr;
#pragma unroll
      for (int i = 0; i < 4; ++i)
#pragma unroll
        for (int r = 0; r < 4; ++r) {
          int n = n0 + wm + i * 16 + quad * 4 + r;
          xrec[(size_t)n * PP + p] = weighted[i][j][r] / (denom[i][j][r] + 1e-8f);
        }
    }
  } else {
#pragma unroll
    for (int i = 0; i < 4; ++i) {
      int n = n0 + wm + i * 16 + lr;
#pragma unroll
      for (int j = 0; j < 2; ++j)
#pragma unroll
        for (int r = 0; r < 4; ++r) {
          int p = p0 + wn + j * 16 + quad * 4 + r;
          xrec[(size_t)n * PP + p] = weighted[i][j][r] / (denom[i][j][r] + 1e-8f);
        }
    }
  }
}

// ---------------------------------------------------------------------------
// fw[n,p,e] fp32 out. One thread per (n,p): 64B contiguous store.
// ---------------------------------------------------------------------------
__global__ void k_fw(const float* __restrict__ gate,
                     const ushort_t* __restrict__ Amat,
                     float* __restrict__ fw) {
  __shared__ float sg[16];
  int n = blockIdx.y;
  int p = blockIdx.x * 256 + threadIdx.x;
  if (threadIdx.x < 16) sg[threadIdx.x] = gate[(size_t)n * EE + threadIdx.x];
  __syncthreads();
  uint4 a0 = *(const uint4*)(Amat + (size_t)p * EE);
  uint4 a1 = *(const uint4*)(Amat + (size_t)p * EE + 8);
  ushort_t av[16];
  *(uint4*)av = a0;
  *(uint4*)(av + 8) = a1;
  float wv[16];
  float s = 0.f;
#pragma unroll
  for (int e = 0; e < 16; ++e) {
    wv[e] = sg[e] * b2f(av[e]);
    s += wv[e];
  }
  float inv = 1.f / (s + 1e-8f);
  float* dst = fw + ((size_t)n * PP + p) * EE;
#pragma unroll
  for (int e = 0; e < 16; ++e) wv[e] *= inv;
  *(float4*)(dst + 0)  = *(float4*)(wv + 0);
  *(float4*)(dst + 4)  = *(float4*)(wv + 4);
  *(float4*)(dst + 8)  = *(float4*)(wv + 8);
  *(float4*)(dst + 12) = *(float4*)(wv + 12);
}

// ---------------------------------------------------------------------------
extern "C" void kernel_launch(void* const* d_in, const int* in_sizes, int n_in,
                              void* d_out, int out_size, void* d_ws,
                              size_t ws_size, hipStream_t stream) {
  const void* z_r   = d_in[0];
  const void* W1_r  = d_in[1];
  const void* b1_r  = d_in[2];
  const void* W2_r  = d_in[3];
  const void* b2_r  = d_in[4];
  const void* W3_r  = d_in[5];
  const void* b3_r  = d_in[6];
  const void* Wg1_r = d_in[7];
  const void* bg1_r = d_in[8];
  const void* Wg2_r = d_in[9];
  const void* bg2_r = d_in[10];
  const void* A_r   = d_in[11];

  float* xrec = (float*)d_out;                       // [N][P] fp32
  float* fw   = (float*)d_out + (size_t)NN * PP;     // [N][P][E] fp32

  char* ws = (char*)d_ws;
  int* flag    = (int*)ws;             ws += 128;
  int* mapflag = (int*)ws;             ws += 128;
  float* gate = (float*)ws;            ws += (size_t)NN * EE * 4;
  ushort_t* zC   = (ushort_t*)ws;      ws += (size_t)NN * DD * 2;
  ushort_t* b1C  = (ushort_t*)ws;      ws += (size_t)EE * HH1 * 2;
  ushort_t* b2C  = (ushort_t*)ws;      ws += (size_t)EE * HH2 * 2;
  ushort_t* b3C  = (ushort_t*)ws;      ws += (size_t)EE * PP * 2;
  ushort_t* AC   = (ushort_t*)ws;      ws += (size_t)PP * EE * 2;
  ushort_t* W1t = (ushort_t*)ws;       ws += (size_t)EE * HH1 * DD * 2;
  ushort_t* W2t = (ushort_t*)ws;       ws += (size_t)EE * HH2 * HH1 * 2;
  ushort_t* W3t = (ushort_t*)ws;       ws += (size_t)EE * PP * HH2 * 2;
  ushort_t* h1  = (ushort_t*)ws;       ws += (size_t)EE * NN * HH1 * 2;
  ushort_t* h2  = (ushort_t*)ws;       ws += (size_t)EE * NN * HH2 * 2;

  // 1. dtype sniff + MFMA layout probe
  k_sniff<<<1, 256, 0, stream>>>((const unsigned int*)z_r, flag);
  k_probe<<<1, 64, 0, stream>>>(mapflag);

  // 2. canonicalize tensors feeding MFMA/epilogues to bf16
  auto cvt = [&](const void* src, ushort_t* dst, int n) {
    int blocks = (n / 8 + 255) / 256;
    if (blocks < 1) blocks = 1;
    k_convert<<<blocks, 256, 0, stream>>>(src, dst, n, flag);
  };
  cvt(z_r,  zC,  NN * DD);
  cvt(b1_r, b1C, EE * HH1);
  cvt(b2_r, b2C, EE * HH2);
  cvt(b3_r, b3C, EE * PP);
  cvt(A_r,  AC,  PP * EE);

  // 3. transpose+convert expert weights to [E][H][K] bf16
  k_transpose_cvt<<<dim3(HH1 / 64, DD / 64, EE), 256, 0, stream>>>(
      W1_r, W1t, DD, HH1, flag);
  k_transpose_cvt<<<dim3(HH2 / 64, HH1 / 64, EE), 256, 0, stream>>>(
      W2_r, W2t, HH1, HH2, flag);
  k_transpose_cvt<<<dim3(PP / 64, HH2 / 64, EE), 256, 0, stream>>>(
      W3_r, W3t, HH2, PP, flag);

  // 4. gate (exact fp32 path from raw inputs)
  k_gate<<<NN / 4, 256, 0, stream>>>(z_r, Wg1_r, bg1_r, Wg2_r, bg2_r, flag, gate);

  // 5. expert MLP layers 1,2 (bf16 MFMA)
  k_gemm_bt_relu<<<dim3(HH1 / 128, NN / 128, EE), 256, 0, stream>>>(
      zC, W1t, b1C, h1, NN, HH1, DD, 0, (long)HH1 * DD, HH1, (long)NN * HH1,
      mapflag);
  k_gemm_bt_relu<<<dim3(HH2 / 128, NN / 128, EE), 256, 0, stream>>>(
      h1, W2t, b2C, h2, NN, HH2, HH1, (long)NN * HH1, (long)HH2 * HH1, HH2,
      (long)NN * HH2, mapflag);

  // 6. layer 3 + gated combine -> x_rec (fp32)
  k_l3_combine<<<dim3(PP / 128, NN / 128), 512, 0, stream>>>(
      h2, W3t, b3C, AC, gate, xrec, mapflag);

  // 7. fw output (fp32)
  k_fw<<<dim3(PP / 256, NN), 256, 0, stream>>>(gate, AC, fw);
}